// Round 11
// baseline (1487.548 us; speedup 1.0000x reference)
//
#include <hip/hip_runtime.h>
#include <hip/hip_bf16.h>
#include <cmath>
#include <cstddef>

// Problem constants (from reference)
#define NN 100000
#define HH 128
#define EE 1600000
#define NH (NN * HH)
#define ALPHA_C 0.1f
#define THETA_C 0.5f
#define EPS_C 1e-5f

constexpr int TR = 64;    // rows per GEMM block
constexpr int AST = 68;   // LDS A^T stride (floats): 16B-aligned rows, b128-clean
constexpr int SCAN_B = 256;
constexpr int NBLK = (NN + SCAN_B - 1) / SCAN_B;   // 391 scan blocks

// ---------------------------------------------------------------------------
__global__ __launch_bounds__(256) void zero_int_k(int* __restrict__ p, int n) {
    int i = blockIdx.x * 256 + threadIdx.x;
    if (i < n) p[i] = 0;
}
__global__ __launch_bounds__(256) void zero_f4_k(float4* __restrict__ p, int n4) {
    int i = blockIdx.x * 256 + threadIdx.x;
    if (i < n4) p[i] = float4{0.f, 0.f, 0.f, 0.f};
}

// ---------------------------------------------------------------------------
// Index dtype detection: int64 (values < 2^31) -> every odd 32-bit word is 0.
__global__ void detect_idx64(const int* __restrict__ p, int* __restrict__ flag) {
    int any = 0;
    for (int i = 0; i < 64; ++i) any |= p[2 * i + 1];
    *flag = (any == 0) ? 1 : 0;
}

__device__ __forceinline__ int load_idx(const void* p, int e, int is64) {
    return is64 ? (int)((const long long*)p)[e] : ((const int*)p)[e];
}

// ---------------------------------------------------------------------------
// CSR build: histogram of dst
__global__ __launch_bounds__(256) void hist_k(
    const void* __restrict__ dstp, const int* __restrict__ flag,
    int* __restrict__ hist)
{
    int e = blockIdx.x * 256 + threadIdx.x;
    if (e >= EE) return;
    atomicAdd(&hist[load_idx(dstp, e, *flag)], 1);
}

__global__ __launch_bounds__(SCAN_B) void scan1_k(
    const int* __restrict__ hist, int* __restrict__ incl, int* __restrict__ bsum)
{
    __shared__ int sh[SCAN_B];
    int t = threadIdx.x;
    int i = blockIdx.x * SCAN_B + t;
    int v = (i < NN) ? hist[i] : 0;
    sh[t] = v;
    __syncthreads();
    for (int off = 1; off < SCAN_B; off <<= 1) {
        int x = (t >= off) ? sh[t - off] : 0;
        __syncthreads();
        sh[t] += x;
        __syncthreads();
    }
    if (i < NN) incl[i] = sh[t];
    if (t == SCAN_B - 1) bsum[blockIdx.x] = sh[t];
}

__global__ __launch_bounds__(512) void scan2_k(int* __restrict__ bsum) {
    __shared__ int sh[512];
    int t = threadIdx.x;
    sh[t] = (t < NBLK) ? bsum[t] : 0;
    __syncthreads();
    for (int off = 1; off < 512; off <<= 1) {
        int x = (t >= off) ? sh[t - off] : 0;
        __syncthreads();
        sh[t] += x;
        __syncthreads();
    }
    if (t < NBLK) bsum[t] = sh[t];
}

__global__ __launch_bounds__(SCAN_B) void scan3_k(
    const int* __restrict__ hist, const int* __restrict__ incl,
    const int* __restrict__ bsum, int* __restrict__ row_ptr,
    int* __restrict__ cursor)
{
    int b = blockIdx.x;
    int i = b * SCAN_B + threadIdx.x;
    if (i < NN) {
        int ex = incl[i] - hist[i] + (b > 0 ? bsum[b - 1] : 0);
        row_ptr[i] = ex;
        cursor[i] = ex;
    }
    if (i == 0) row_ptr[NN] = EE;
}

__global__ __launch_bounds__(256) void fill_k(
    const void* __restrict__ srcp, const void* __restrict__ dstp,
    const int* __restrict__ flag, int* __restrict__ cursor,
    int* __restrict__ sorted_src)
{
    int e = blockIdx.x * 256 + threadIdx.x;
    if (e >= EE) return;
    int is64 = *flag;
    int d = load_idx(dstp, e, is64);
    int pos = atomicAdd(&cursor[d], 1);
    sorted_src[pos] = load_idx(srcp, e, is64);
}

// ---------------------------------------------------------------------------
// Weight prep: Wp[i] = W_in (i==0) else (1-bl_i)*I + bl_i*conv_W[i-1]
__global__ __launch_bounds__(256) void prep_w(
    const float* __restrict__ W_in, const float* __restrict__ conv_W,
    float* __restrict__ Wp)
{
    int i = blockIdx.y;                          // 0..5
    int idx = blockIdx.x * 256 + threadIdx.x;    // 0..16383
    float v;
    if (i == 0) {
        v = W_in[idx];
    } else {
        float bl = logf(THETA_C / (float)i + 1.f);
        int k = idx >> 7, c = idx & 127;
        v = bl * conv_W[(size_t)(i - 1) * 16384 + idx] + ((k == c) ? (1.f - bl) : 0.f);
    }
    Wp[(size_t)i * 16384 + idx] = v;
}

// ---------------------------------------------------------------------------
// 128-col GEMM, r5 verbatim (verified: 64 VGPR, (256,4), no scratch). Used
// only for x0 = x @ W_in + b_in. DO NOT restructure (r1/r2/r8 evidence).
__global__ __launch_bounds__(256, 4) void gemm128(
    const float* __restrict__ A, const float* __restrict__ Wp,
    const float* __restrict__ bias, float* __restrict__ out,
    float* __restrict__ statsp, int nrows)
{
    __shared__ float As[HH * AST];   // A^T [k][r]
    const int t = threadIdx.x;
    const int tx = t & 31;           // output cols 4*tx..4*tx+3
    const int ty = t >> 5;           // rows 8*ty..8*ty+7
    const int lane = t & 63, w = t >> 6;
    const int row0 = blockIdx.x * TR;

#pragma unroll
    for (int i = 0; i < 8; ++i) {
        int r = (i & 3) * 16 + (lane & 15);
        int k4 = ((i >> 2) * 4 + w) * 4 + (lane >> 4);
        float4 v = {0.f, 0.f, 0.f, 0.f};
        if (row0 + r < nrows)
            v = ((const float4*)(A + (size_t)(row0 + r) * HH))[k4];
        int k = k4 * 4;
        As[(k + 0) * AST + r] = v.x;
        As[(k + 1) * AST + r] = v.y;
        As[(k + 2) * AST + r] = v.z;
        As[(k + 3) * AST + r] = v.w;
    }
    __syncthreads();

    float acc[8][4];
#pragma unroll
    for (int ii = 0; ii < 8; ++ii)
#pragma unroll
        for (int j = 0; j < 4; ++j) acc[ii][j] = 0.f;

    const float4* W4 = (const float4*)Wp;   // row k -> W4[k*32 + tx]
    float4 wbuf[4];
#pragma unroll
    for (int kk = 0; kk < 4; ++kk) wbuf[kk] = W4[kk * 32 + tx];

    for (int k0 = 0; k0 < HH; k0 += 4) {
        float4 wn[4];
        const bool more = (k0 + 4 < HH);
#pragma unroll
        for (int kk = 0; kk < 4; ++kk) {
            if (more) wn[kk] = W4[(k0 + 4 + kk) * 32 + tx];  // prefetch next chunk
            int k = k0 + kk;
            const float* ap = &As[k * AST + ty * 8];
            float4 a0 = *(const float4*)ap;
            float4 a1 = *(const float4*)(ap + 4);
            float a[8] = {a0.x, a0.y, a0.z, a0.w, a1.x, a1.y, a1.z, a1.w};
#pragma unroll
            for (int ii = 0; ii < 8; ++ii) {
                acc[ii][0] += a[ii] * wbuf[kk].x;
                acc[ii][1] += a[ii] * wbuf[kk].y;
                acc[ii][2] += a[ii] * wbuf[kk].z;
                acc[ii][3] += a[ii] * wbuf[kk].w;
            }
        }
        if (more) {
#pragma unroll
            for (int kk = 0; kk < 4; ++kk) wbuf[kk] = wn[kk];
        }
    }

    float4 b4 = {0.f, 0.f, 0.f, 0.f};
    if (bias) b4 = ((const float4*)bias)[tx];
#pragma unroll
    for (int ii = 0; ii < 8; ++ii) {
        int r = row0 + ty * 8 + ii;
        if (r < nrows) {
            float4 v = {acc[ii][0] + b4.x, acc[ii][1] + b4.y,
                        acc[ii][2] + b4.z, acc[ii][3] + b4.w};
            ((float4*)out)[(size_t)r * 32 + tx] = v;
        }
    }
    (void)statsp;
}

// ---------------------------------------------------------------------------
// Gather phase (shared by fused kernels): wave w gathers its 16 nodes into
// the As[k][r] tile (transposed), applying optional BN+ReLU and the residual
// fold. r9-verified 8-deep edge loop. Expanded inline via macro-free copies
// in both kernels below (no lambdas/device-fns capturing frames -- r3/r4
// lesson).

// FUSED layer kernel (r10-verified): phase A gather -> As, phase B GEMM.
template <bool BN, bool DOSTATS>
__global__ __launch_bounds__(256, 2) void fused_layer(
    const float* __restrict__ z, const int* __restrict__ row_ptr,
    const int* __restrict__ sorted_src,
    const float* __restrict__ stats,    // [256] sum,sumsq of z (BN only)
    const float* __restrict__ gamma, const float* __restrict__ beta,
    const float* __restrict__ resid,    // x0
    const float* __restrict__ Wp, float* __restrict__ out,
    float* __restrict__ statsp, int nrows)
{
    __shared__ float As[HH * AST];   // A^T [k][r]
    const int t = threadIdx.x;
    const int tx = t & 31;           // output cols 4*tx..4*tx+3
    const int ty = t >> 5;           // rows 8*ty..8*ty+7
    const int lane = t & 63, w = t >> 6;
    const int row0 = blockIdx.x * TR;

    const int half = lane >> 5;      // edge stream of the pair
    const int c4 = lane & 31;        // float4 channel index

    float4 sc = {1.f, 1.f, 1.f, 1.f}, sh = {0.f, 0.f, 0.f, 0.f};
    if (BN) {
        const float invN = 1.f / (float)NN;
        float4 s  = ((const float4*)stats)[c4];
        float4 s2 = ((const float4*)(stats + 128))[c4];
        float4 g  = ((const float4*)gamma)[c4];
        float4 b  = ((const float4*)beta)[c4];
        float m, var;
        m = s.x * invN; var = s2.x * invN - m * m;
        sc.x = rsqrtf(var + EPS_C) * g.x; sh.x = b.x - m * sc.x;
        m = s.y * invN; var = s2.y * invN - m * m;
        sc.y = rsqrtf(var + EPS_C) * g.y; sh.y = b.y - m * sc.y;
        m = s.z * invN; var = s2.z * invN - m * m;
        sc.z = rsqrtf(var + EPS_C) * g.z; sh.z = b.z - m * sc.z;
        m = s.w * invN; var = s2.w * invN - m * m;
        sc.w = rsqrtf(var + EPS_C) * g.w; sh.w = b.w - m * sc.w;
    }

    // ---- phase A: gather 16 nodes per wave into As (transposed) ----
    for (int i = 0; i < 16; ++i) {
        int rr = w * 16 + i;
        int node = row0 + rr;
        if (node < nrows) {
            float4 r4v = ((const float4*)(resid + (size_t)node * HH))[c4];
            int e1 = row_ptr[node + 1];
            int e = row_ptr[node] + half;
            float4 acc  = {0.f, 0.f, 0.f, 0.f};
            float4 acc2 = {0.f, 0.f, 0.f, 0.f};
            float4 acc3 = {0.f, 0.f, 0.f, 0.f};
            float4 acc4 = {0.f, 0.f, 0.f, 0.f};
            for (; e + 6 < e1; e += 8) {
                int s0 = sorted_src[e];
                int s1 = sorted_src[e + 2];
                int s2 = sorted_src[e + 4];
                int s3 = sorted_src[e + 6];
                float4 v0 = ((const float4*)(z + (size_t)s0 * HH))[c4];
                float4 v1 = ((const float4*)(z + (size_t)s1 * HH))[c4];
                float4 v2 = ((const float4*)(z + (size_t)s2 * HH))[c4];
                float4 v3 = ((const float4*)(z + (size_t)s3 * HH))[c4];
                if (BN) {
                    v0.x = fmaxf(0.f, v0.x * sc.x + sh.x);
                    v0.y = fmaxf(0.f, v0.y * sc.y + sh.y);
                    v0.z = fmaxf(0.f, v0.z * sc.z + sh.z);
                    v0.w = fmaxf(0.f, v0.w * sc.w + sh.w);
                    v1.x = fmaxf(0.f, v1.x * sc.x + sh.x);
                    v1.y = fmaxf(0.f, v1.y * sc.y + sh.y);
                    v1.z = fmaxf(0.f, v1.z * sc.z + sh.z);
                    v1.w = fmaxf(0.f, v1.w * sc.w + sh.w);
                    v2.x = fmaxf(0.f, v2.x * sc.x + sh.x);
                    v2.y = fmaxf(0.f, v2.y * sc.y + sh.y);
                    v2.z = fmaxf(0.f, v2.z * sc.z + sh.z);
                    v2.w = fmaxf(0.f, v2.w * sc.w + sh.w);
                    v3.x = fmaxf(0.f, v3.x * sc.x + sh.x);
                    v3.y = fmaxf(0.f, v3.y * sc.y + sh.y);
                    v3.z = fmaxf(0.f, v3.z * sc.z + sh.z);
                    v3.w = fmaxf(0.f, v3.w * sc.w + sh.w);
                }
                acc.x  += v0.x; acc.y  += v0.y; acc.z  += v0.z; acc.w  += v0.w;
                acc2.x += v1.x; acc2.y += v1.y; acc2.z += v1.z; acc2.w += v1.w;
                acc3.x += v2.x; acc3.y += v2.y; acc3.z += v2.z; acc3.w += v2.w;
                acc4.x += v3.x; acc4.y += v3.y; acc4.z += v3.z; acc4.w += v3.w;
            }
            for (; e + 2 < e1; e += 4) {
                int s0 = sorted_src[e];
                int s1 = sorted_src[e + 2];
                float4 v0 = ((const float4*)(z + (size_t)s0 * HH))[c4];
                float4 v1 = ((const float4*)(z + (size_t)s1 * HH))[c4];
                if (BN) {
                    v0.x = fmaxf(0.f, v0.x * sc.x + sh.x);
                    v0.y = fmaxf(0.f, v0.y * sc.y + sh.y);
                    v0.z = fmaxf(0.f, v0.z * sc.z + sh.z);
                    v0.w = fmaxf(0.f, v0.w * sc.w + sh.w);
                    v1.x = fmaxf(0.f, v1.x * sc.x + sh.x);
                    v1.y = fmaxf(0.f, v1.y * sc.y + sh.y);
                    v1.z = fmaxf(0.f, v1.z * sc.z + sh.z);
                    v1.w = fmaxf(0.f, v1.w * sc.w + sh.w);
                }
                acc.x  += v0.x; acc.y  += v0.y; acc.z  += v0.z; acc.w  += v0.w;
                acc2.x += v1.x; acc2.y += v1.y; acc2.z += v1.z; acc2.w += v1.w;
            }
            if (e < e1) {
                int s = sorted_src[e];
                float4 v = ((const float4*)(z + (size_t)s * HH))[c4];
                if (BN) {
                    v.x = fmaxf(0.f, v.x * sc.x + sh.x);
                    v.y = fmaxf(0.f, v.y * sc.y + sh.y);
                    v.z = fmaxf(0.f, v.z * sc.z + sh.z);
                    v.w = fmaxf(0.f, v.w * sc.w + sh.w);
                }
                acc.x += v.x; acc.y += v.y; acc.z += v.z; acc.w += v.w;
            }
            acc.x += acc2.x + acc3.x + acc4.x;
            acc.y += acc2.y + acc3.y + acc4.y;
            acc.z += acc2.z + acc3.z + acc4.z;
            acc.w += acc2.w + acc3.w + acc4.w;
            acc.x += __shfl_down(acc.x, 32);
            acc.y += __shfl_down(acc.y, 32);
            acc.z += __shfl_down(acc.z, 32);
            acc.w += __shfl_down(acc.w, 32);
            if (half == 0) {
                const float cA = 1.f - ALPHA_C, cB = ALPHA_C;
                int k = c4 * 4;
                As[(k + 0) * AST + rr] = cA * acc.x + cB * r4v.x;
                As[(k + 1) * AST + rr] = cA * acc.y + cB * r4v.y;
                As[(k + 2) * AST + rr] = cA * acc.z + cB * r4v.z;
                As[(k + 3) * AST + rr] = cA * acc.w + cB * r4v.w;
            }
        }
    }
    __syncthreads();

    // ---- phase B: r5-verified GEMM inner loop ----
    float acc[8][4];
#pragma unroll
    for (int ii = 0; ii < 8; ++ii)
#pragma unroll
        for (int j = 0; j < 4; ++j) acc[ii][j] = 0.f;

    const float4* W4 = (const float4*)Wp;   // row k -> W4[k*32 + tx]
    float4 wbuf[4];
#pragma unroll
    for (int kk = 0; kk < 4; ++kk) wbuf[kk] = W4[kk * 32 + tx];

    for (int k0 = 0; k0 < HH; k0 += 4) {
        float4 wn[4];
        const bool more = (k0 + 4 < HH);
#pragma unroll
        for (int kk = 0; kk < 4; ++kk) {
            if (more) wn[kk] = W4[(k0 + 4 + kk) * 32 + tx];
            int k = k0 + kk;
            const float* ap = &As[k * AST + ty * 8];
            float4 a0 = *(const float4*)ap;
            float4 a1 = *(const float4*)(ap + 4);
            float a[8] = {a0.x, a0.y, a0.z, a0.w, a1.x, a1.y, a1.z, a1.w};
#pragma unroll
            for (int ii = 0; ii < 8; ++ii) {
                acc[ii][0] += a[ii] * wbuf[kk].x;
                acc[ii][1] += a[ii] * wbuf[kk].y;
                acc[ii][2] += a[ii] * wbuf[kk].z;
                acc[ii][3] += a[ii] * wbuf[kk].w;
            }
        }
        if (more) {
#pragma unroll
            for (int kk = 0; kk < 4; ++kk) wbuf[kk] = wn[kk];
        }
    }

    float cs[4] = {0.f, 0.f, 0.f, 0.f}, cq[4] = {0.f, 0.f, 0.f, 0.f};
#pragma unroll
    for (int ii = 0; ii < 8; ++ii) {
        int r = row0 + ty * 8 + ii;
        if (r < nrows) {
            float4 v = {acc[ii][0], acc[ii][1], acc[ii][2], acc[ii][3]};
            ((float4*)out)[(size_t)r * 32 + tx] = v;
            if (DOSTATS) {
                cs[0] += v.x; cq[0] += v.x * v.x;
                cs[1] += v.y; cq[1] += v.y * v.y;
                cs[2] += v.z; cq[2] += v.z * v.z;
                cs[3] += v.w; cq[3] += v.w * v.w;
            }
        }
    }
    if (DOSTATS) {
        __syncthreads();              // all waves done with As -> reuse as scratch
        float* red = As;              // [0..1023]=sum, [1024..2047]=sumsq
#pragma unroll
        for (int j = 0; j < 4; ++j) {
            red[ty * 128 + tx * 4 + j] = cs[j];
            red[1024 + ty * 128 + tx * 4 + j] = cq[j];
        }
        __syncthreads();
        if (t < 128) {
            float s = 0.f, q = 0.f;
#pragma unroll
            for (int g = 0; g < 8; ++g) {
                s += red[g * 128 + t];
                q += red[1024 + g * 128 + t];
            }
            atomicAdd(&statsp[t], s);
            atomicAdd(&statsp[128 + t], q);
        }
    }
}

// ---------------------------------------------------------------------------
// FUSED layer-3 + JumpingKnowledge kernel:
//   phase A: gather (BN path) into As            [r10-verified code]
//   phase B: z3 block = As @ Wl  -> acc          [r5-verified loop]
//   phase T: barrier; write acc back into As transposed (z3 never touches
//            global memory); barrier
//   phase C: JK = z3-part (from As, Wjk[3]) then z0,z1,z2 staged from global
//            [gemm_jk-verified staging + inner loop]; out = acc + bjk.
// Saves the gemm_jk launch and the 51MB write + 51MB read of z3.
// (256,2): proven no-spill bound; peak live ~100 VGPR (phase-B acc dead
// before phase C); LDS 34816 -> 4 blocks/CU.
__global__ __launch_bounds__(256, 2) void fused_l3_jk(
    const float* __restrict__ z, const int* __restrict__ row_ptr,
    const int* __restrict__ sorted_src,
    const float* __restrict__ stats, const float* __restrict__ gamma,
    const float* __restrict__ beta, const float* __restrict__ resid,
    const float* __restrict__ Wl,       // layer-3 prepped weight
    const float* __restrict__ z0, const float* __restrict__ z1,
    const float* __restrict__ z2, const float* __restrict__ Wjk,
    const float* __restrict__ bjk, float* out, int nrows)
{
    __shared__ float As[HH * AST];
    const int t = threadIdx.x;
    const int tx = t & 31;
    const int ty = t >> 5;
    const int lane = t & 63, w = t >> 6;
    const int row0 = blockIdx.x * TR;
    const int half = lane >> 5;
    const int c4 = lane & 31;

    // BN scale/shift
    float4 sc, sh;
    {
        const float invN = 1.f / (float)NN;
        float4 s  = ((const float4*)stats)[c4];
        float4 s2 = ((const float4*)(stats + 128))[c4];
        float4 g  = ((const float4*)gamma)[c4];
        float4 b  = ((const float4*)beta)[c4];
        float m, var;
        m = s.x * invN; var = s2.x * invN - m * m;
        sc.x = rsqrtf(var + EPS_C) * g.x; sh.x = b.x - m * sc.x;
        m = s.y * invN; var = s2.y * invN - m * m;
        sc.y = rsqrtf(var + EPS_C) * g.y; sh.y = b.y - m * sc.y;
        m = s.z * invN; var = s2.z * invN - m * m;
        sc.z = rsqrtf(var + EPS_C) * g.z; sh.z = b.z - m * sc.z;
        m = s.w * invN; var = s2.w * invN - m * m;
        sc.w = rsqrtf(var + EPS_C) * g.w; sh.w = b.w - m * sc.w;
    }

    // ---- phase A: gather 16 nodes per wave into As (transposed) ----
    for (int i = 0; i < 16; ++i) {
        int rr = w * 16 + i;
        int node = row0 + rr;
        if (node < nrows) {
            float4 r4v = ((const float4*)(resid + (size_t)node * HH))[c4];
            int e1 = row_ptr[node + 1];
            int e = row_ptr[node] + half;
            float4 acc  = {0.f, 0.f, 0.f, 0.f};
            float4 acc2 = {0.f, 0.f, 0.f, 0.f};
            float4 acc3 = {0.f, 0.f, 0.f, 0.f};
            float4 acc4 = {0.f, 0.f, 0.f, 0.f};
            for (; e + 6 < e1; e += 8) {
                int s0 = sorted_src[e];
                int s1 = sorted_src[e + 2];
                int s2 = sorted_src[e + 4];
                int s3 = sorted_src[e + 6];
                float4 v0 = ((const float4*)(z + (size_t)s0 * HH))[c4];
                float4 v1 = ((const float4*)(z + (size_t)s1 * HH))[c4];
                float4 v2 = ((const float4*)(z + (size_t)s2 * HH))[c4];
                float4 v3 = ((const float4*)(z + (size_t)s3 * HH))[c4];
                v0.x = fmaxf(0.f, v0.x * sc.x + sh.x);
                v0.y = fmaxf(0.f, v0.y * sc.y + sh.y);
                v0.z = fmaxf(0.f, v0.z * sc.z + sh.z);
                v0.w = fmaxf(0.f, v0.w * sc.w + sh.w);
                v1.x = fmaxf(0.f, v1.x * sc.x + sh.x);
                v1.y = fmaxf(0.f, v1.y * sc.y + sh.y);
                v1.z = fmaxf(0.f, v1.z * sc.z + sh.z);
                v1.w = fmaxf(0.f, v1.w * sc.w + sh.w);
                v2.x = fmaxf(0.f, v2.x * sc.x + sh.x);
                v2.y = fmaxf(0.f, v2.y * sc.y + sh.y);
                v2.z = fmaxf(0.f, v2.z * sc.z + sh.z);
                v2.w = fmaxf(0.f, v2.w * sc.w + sh.w);
                v3.x = fmaxf(0.f, v3.x * sc.x + sh.x);
                v3.y = fmaxf(0.f, v3.y * sc.y + sh.y);
                v3.z = fmaxf(0.f, v3.z * sc.z + sh.z);
                v3.w = fmaxf(0.f, v3.w * sc.w + sh.w);
                acc.x  += v0.x; acc.y  += v0.y; acc.z  += v0.z; acc.w  += v0.w;
                acc2.x += v1.x; acc2.y += v1.y; acc2.z += v1.z; acc2.w += v1.w;
                acc3.x += v2.x; acc3.y += v2.y; acc3.z += v2.z; acc3.w += v2.w;
                acc4.x += v3.x; acc4.y += v3.y; acc4.z += v3.z; acc4.w += v3.w;
            }
            for (; e + 2 < e1; e += 4) {
                int s0 = sorted_src[e];
                int s1 = sorted_src[e + 2];
                float4 v0 = ((const float4*)(z + (size_t)s0 * HH))[c4];
                float4 v1 = ((const float4*)(z + (size_t)s1 * HH))[c4];
                v0.x = fmaxf(0.f, v0.x * sc.x + sh.x);
                v0.y = fmaxf(0.f, v0.y * sc.y + sh.y);
                v0.z = fmaxf(0.f, v0.z * sc.z + sh.z);
                v0.w = fmaxf(0.f, v0.w * sc.w + sh.w);
                v1.x = fmaxf(0.f, v1.x * sc.x + sh.x);
                v1.y = fmaxf(0.f, v1.y * sc.y + sh.y);
                v1.z = fmaxf(0.f, v1.z * sc.z + sh.z);
                v1.w = fmaxf(0.f, v1.w * sc.w + sh.w);
                acc.x  += v0.x; acc.y  += v0.y; acc.z  += v0.z; acc.w  += v0.w;
                acc2.x += v1.x; acc2.y += v1.y; acc2.z += v1.z; acc2.w += v1.w;
            }
            if (e < e1) {
                int s = sorted_src[e];
                float4 v = ((const float4*)(z + (size_t)s * HH))[c4];
                v.x = fmaxf(0.f, v.x * sc.x + sh.x);
                v.y = fmaxf(0.f, v.y * sc.y + sh.y);
                v.z = fmaxf(0.f, v.z * sc.z + sh.z);
                v.w = fmaxf(0.f, v.w * sc.w + sh.w);
                acc.x += v.x; acc.y += v.y; acc.z += v.z; acc.w += v.w;
            }
            acc.x += acc2.x + acc3.x + acc4.x;
            acc.y += acc2.y + acc3.y + acc4.y;
            acc.z += acc2.z + acc3.z + acc4.z;
            acc.w += acc2.w + acc3.w + acc4.w;
            acc.x += __shfl_down(acc.x, 32);
            acc.y += __shfl_down(acc.y, 32);
            acc.z += __shfl_down(acc.z, 32);
            acc.w += __shfl_down(acc.w, 32);
            if (half == 0) {
                const float cA = 1.f - ALPHA_C, cB = ALPHA_C;
                int k = c4 * 4;
                As[(k + 0) * AST + rr] = cA * acc.x + cB * r4v.x;
                As[(k + 1) * AST + rr] = cA * acc.y + cB * r4v.y;
                As[(k + 2) * AST + rr] = cA * acc.z + cB * r4v.z;
                As[(k + 3) * AST + rr] = cA * acc.w + cB * r4v.w;
            }
        }
    }
    __syncthreads();

    // ---- phase B: z3 block = As @ Wl ----
    float acc[8][4];
#pragma unroll
    for (int ii = 0; ii < 8; ++ii)
#pragma unroll
        for (int j = 0; j < 4; ++j) acc[ii][j] = 0.f;
    {
        const float4* W4 = (const float4*)Wl;
        float4 wbuf[4];
#pragma unroll
        for (int kk = 0; kk < 4; ++kk) wbuf[kk] = W4[kk * 32 + tx];
        for (int k0 = 0; k0 < HH; k0 += 4) {
            float4 wn[4];
            const bool more = (k0 + 4 < HH);
#pragma unroll
            for (int kk = 0; kk < 4; ++kk) {
                if (more) wn[kk] = W4[(k0 + 4 + kk) * 32 + tx];
                int k = k0 + kk;
                const float* ap = &As[k * AST + ty * 8];
                float4 a0 = *(const float4*)ap;
                float4 a1 = *(const float4*)(ap + 4);
                float a[8] = {a0.x, a0.y, a0.z, a0.w, a1.x, a1.y, a1.z, a1.w};
#pragma unroll
                for (int ii = 0; ii < 8; ++ii) {
                    acc[ii][0] += a[ii] * wbuf[kk].x;
                    acc[ii][1] += a[ii] * wbuf[kk].y;
                    acc[ii][2] += a[ii] * wbuf[kk].z;
                    acc[ii][3] += a[ii] * wbuf[kk].w;
                }
            }
            if (more) {
#pragma unroll
                for (int kk = 0; kk < 4; ++kk) wbuf[kk] = wn[kk];
            }
        }
    }

    // ---- phase T: z3 -> As (transposed), in-LDS only ----
    __syncthreads();                 // all waves done reading As
#pragma unroll
    for (int ii = 0; ii < 8; ++ii) {
#pragma unroll
        for (int j = 0; j < 4; ++j)
            As[(tx * 4 + j) * AST + ty * 8 + ii] = acc[ii][j];
    }
    __syncthreads();

    // ---- phase C: JumpingKnowledge ----
    float ajk[8][4];
#pragma unroll
    for (int ii = 0; ii < 8; ++ii)
#pragma unroll
        for (int j = 0; j < 4; ++j) ajk[ii][j] = 0.f;

    // source 3 (z3) from As
    {
        const float4* W4 = (const float4*)(Wjk + (size_t)3 * 128 * HH);
        float4 wbuf[4];
#pragma unroll
        for (int kk = 0; kk < 4; ++kk) wbuf[kk] = W4[kk * 32 + tx];
        for (int k0 = 0; k0 < HH; k0 += 4) {
            float4 wn[4];
            const bool more = (k0 + 4 < HH);
#pragma unroll
            for (int kk = 0; kk < 4; ++kk) {
                if (more) wn[kk] = W4[(k0 + 4 + kk) * 32 + tx];
                int k = k0 + kk;
                const float* ap = &As[k * AST + ty * 8];
                float4 a0 = *(const float4*)ap;
                float4 a1 = *(const float4*)(ap + 4);
                float a[8] = {a0.x, a0.y, a0.z, a0.w, a1.x, a1.y, a1.z, a1.w};
#pragma unroll
                for (int ii = 0; ii < 8; ++ii) {
                    ajk[ii][0] += a[ii] * wbuf[kk].x;
                    ajk[ii][1] += a[ii] * wbuf[kk].y;
                    ajk[ii][2] += a[ii] * wbuf[kk].z;
                    ajk[ii][3] += a[ii] * wbuf[kk].w;
                }
            }
            if (more) {
#pragma unroll
                for (int kk = 0; kk < 4; ++kk) wbuf[kk] = wn[kk];
            }
        }
    }

    // sources 0..2 staged from global (gemm_jk-verified pattern)
    const float* srcs[3] = {z0, z1, z2};
    for (int j = 0; j < 3; ++j) {
        __syncthreads();
        const float* Z = srcs[j];
#pragma unroll
        for (int i = 0; i < 8; ++i) {
            int r = (i & 3) * 16 + (lane & 15);
            int k4 = ((i >> 2) * 4 + w) * 4 + (lane >> 4);
            float4 v = {0.f, 0.f, 0.f, 0.f};
            if (row0 + r < nrows)
                v = ((const float4*)(Z + (size_t)(row0 + r) * HH))[k4];
            int k = k4 * 4;
            As[(k + 0) * AST + r] = v.x;
            As[(k + 1) * AST + r] = v.y;
            As[(k + 2) * AST + r] = v.z;
            As[(k + 3) * AST + r] = v.w;
        }
        __syncthreads();

        const float4* W4 = (const float4*)(Wjk + (size_t)j * 128 * HH);
        float4 wbuf[4];
#pragma unroll
        for (int kk = 0; kk < 4; ++kk) wbuf[kk] = W4[kk * 32 + tx];
        for (int k0 = 0; k0 < HH; k0 += 4) {
            float4 wn[4];
            const bool more = (k0 + 4 < HH);
#pragma unroll
            for (int kk = 0; kk < 4; ++kk) {
                if (more) wn[kk] = W4[(k0 + 4 + kk) * 32 + tx];
                int k = k0 + kk;
                const float* ap = &As[k * AST + ty * 8];
                float4 a0 = *(const float4*)ap;
                float4 a1 = *(const float4*)(ap + 4);
                float a[8] = {a0.x, a0.y, a0.z, a0.w, a1.x, a1.y, a1.z, a1.w};
#pragma unroll
                for (int ii = 0; ii < 8; ++ii) {
                    ajk[ii][0] += a[ii] * wbuf[kk].x;
                    ajk[ii][1] += a[ii] * wbuf[kk].y;
                    ajk[ii][2] += a[ii] * wbuf[kk].z;
                    ajk[ii][3] += a[ii] * wbuf[kk].w;
                }
            }
            if (more) {
#pragma unroll
                for (int kk = 0; kk < 4; ++kk) wbuf[kk] = wn[kk];
            }
        }
    }

    float4 b4 = ((const float4*)bjk)[tx];
#pragma unroll
    for (int ii = 0; ii < 8; ++ii) {
        int r = row0 + ty * 8 + ii;
        if (r < nrows) {
            float4 v = {ajk[ii][0] + b4.x, ajk[ii][1] + b4.y,
                        ajk[ii][2] + b4.z, ajk[ii][3] + b4.w};
            ((float4*)out)[(size_t)r * 32 + tx] = v;
        }
    }
}

// ---------------------------------------------------------------------------
extern "C" void kernel_launch(void* const* d_in, const int* in_sizes, int n_in,
                              void* d_out, int out_size, void* d_ws, size_t ws_size,
                              hipStream_t stream)
{
    const float* x       = (const float*)d_in[0];
    const float* W_in    = (const float*)d_in[1];
    const float* b_in    = (const float*)d_in[2];
    const float* conv_W  = (const float*)d_in[3];
    const float* bn_g    = (const float*)d_in[4];
    const float* bn_b    = (const float*)d_in[5];
    const float* W_jk    = (const float*)d_in[6];
    const float* b_jk    = (const float*)d_in[7];
    const void*  srcp    = d_in[8];
    const void*  dstp    = d_in[9];

    // Workspace: 5*NH floats (244 MiB) + stats3 + CSR (~7.3 MB) + Wp (384 KB)
    float* ws     = (float*)d_ws;
    float* x0     = ws;                        // [N,H] z0, residual
    float* zs0    = ws + 2 * (size_t)NH;       // z per layer; zs0 reused as JK out
    float* zs1    = ws + 3 * (size_t)NH;
    float* zs2    = ws + 4 * (size_t)NH;
    float* stats3 = ws + 5 * (size_t)NH;       // [3][256] sum/sumsq per BN layer
    int*   flag       = (int*)(stats3 + 768);
    int*   hist       = flag + 1;              // [NN]
    int*   incl       = hist + NN;             // [NN]
    int*   row_ptr    = incl + NN;             // [NN+1]
    int*   cursor     = row_ptr + NN + 1;      // [NN]
    int*   bsum       = cursor + NN;           // [NBLK]
    int*   sorted_src = bsum + NBLK + 1;       // [EE]
    float* Wp         = (float*)(sorted_src + EE);  // [6][128][128]

    const int GEMM_GRID = (NN + TR - 1) / TR;     // 1563
    const int EDGE_GRID = (EE + 255) / 256;       // 6250

    // ---- CSR build + weight prep + stats zero (once per launch) ----
    detect_idx64<<<1, 1, 0, stream>>>((const int*)srcp, flag);
    zero_int_k<<<(NN + 255) / 256, 256, 0, stream>>>(hist, NN);
    zero_f4_k<<<1, 192, 0, stream>>>((float4*)stats3, 192);
    hist_k<<<EDGE_GRID, 256, 0, stream>>>(dstp, flag, hist);
    scan1_k<<<NBLK, SCAN_B, 0, stream>>>(hist, incl, bsum);
    scan2_k<<<1, 512, 0, stream>>>(bsum);
    scan3_k<<<NBLK, SCAN_B, 0, stream>>>(hist, incl, bsum, row_ptr, cursor);
    fill_k<<<EDGE_GRID, 256, 0, stream>>>(srcp, dstp, flag, cursor, sorted_src);
    prep_w<<<dim3(64, 6), 256, 0, stream>>>(W_in, conv_W, Wp);

    // ---- x0 = x @ W_in + b_in ----
    gemm128<<<GEMM_GRID, 256, 0, stream>>>(x, Wp, b_in, x0, nullptr, NN);

    // ---- layer 0: act = x0 (no BN), out zs0, stats0 ----
    fused_layer<false, true><<<GEMM_GRID, 256, 0, stream>>>(
        x0, row_ptr, sorted_src, nullptr, nullptr, nullptr, x0,
        Wp + 1 * 16384, zs0, stats3 + 0, NN);
    // ---- layer 1: BN(stats0), out zs1, stats1 ----
    fused_layer<true, true><<<GEMM_GRID, 256, 0, stream>>>(
        zs0, row_ptr, sorted_src, stats3 + 0, bn_g + 0, bn_b + 0, x0,
        Wp + 2 * 16384, zs1, stats3 + 256, NN);
    // ---- layer 2: BN(stats1), out zs2, stats2 ----
    fused_layer<true, true><<<GEMM_GRID, 256, 0, stream>>>(
        zs1, row_ptr, sorted_src, stats3 + 256, bn_g + HH, bn_b + HH, x0,
        Wp + 3 * 16384, zs2, stats3 + 512, NN);
    // ---- layer 3 + JumpingKnowledge fused: zs0 = JK(z0..z3) ----
    fused_l3_jk<<<GEMM_GRID, 256, 0, stream>>>(
        zs2, row_ptr, sorted_src, stats3 + 512, bn_g + 2 * HH, bn_b + 2 * HH,
        x0, Wp + 4 * 16384, zs0, zs1, zs2, W_jk, b_jk, zs0, NN);
    // ---- layer 4: act = zs0 (no BN), out d_out ----
    fused_layer<false, false><<<GEMM_GRID, 256, 0, stream>>>(
        zs0, row_ptr, sorted_src, nullptr, nullptr, nullptr, x0,
        Wp + 5 * 16384, (float*)d_out, nullptr, NN);
}

// Round 12
// 1448.636 us; speedup vs baseline: 1.0269x; 1.0269x over previous
//
#include <hip/hip_runtime.h>
#include <hip/hip_bf16.h>
#include <cmath>
#include <cstddef>

// Problem constants (from reference)
#define NN 100000
#define HH 128
#define EE 1600000
#define NH (NN * HH)
#define ALPHA_C 0.1f
#define THETA_C 0.5f
#define EPS_C 1e-5f

constexpr int TR = 64;    // rows per GEMM block
constexpr int AST = 68;   // LDS A^T stride (floats): 16B-aligned rows, b128-clean
constexpr int SCAN_B = 256;
constexpr int NBLK = (NN + SCAN_B - 1) / SCAN_B;   // 391 scan blocks

// ---------------------------------------------------------------------------
// Merged prologue: index-dtype detect (1 thread), hist zero, stats zero, and
// weight prep (blocks 0..383), all independent -> one launch instead of four.
// Wp[i] = W_in (i==0) else (1-bl_i)*I + bl_i*conv_W[i-1]
__global__ __launch_bounds__(256) void init_k(
    const int* __restrict__ srcp_i, int* __restrict__ flag,
    int* __restrict__ hist, float* __restrict__ stats3,
    const float* __restrict__ W_in, const float* __restrict__ conv_W,
    float* __restrict__ Wp)
{
    const int b = blockIdx.x, t = threadIdx.x;
    const int i = b * 256 + t;
    if (i < NN) hist[i] = 0;
    if (i < 768) stats3[i] = 0.f;
    if (i == 0) {
        // int64 (values < 2^31) -> every odd 32-bit word is 0
        int any = 0;
        for (int k = 0; k < 64; ++k) any |= srcp_i[2 * k + 1];
        *flag = (any == 0) ? 1 : 0;
    }
    if (b < 384) {
        int wi = b >> 6;                         // 0..5
        int idx = (b & 63) * 256 + t;            // 0..16383
        float v;
        if (wi == 0) {
            v = W_in[idx];
        } else {
            float bl = logf(THETA_C / (float)wi + 1.f);
            int k = idx >> 7, c = idx & 127;
            v = bl * conv_W[(size_t)(wi - 1) * 16384 + idx]
                + ((k == c) ? (1.f - bl) : 0.f);
        }
        Wp[(size_t)wi * 16384 + idx] = v;
    }
}

__device__ __forceinline__ int load_idx(const void* p, int e, int is64) {
    return is64 ? (int)((const long long*)p)[e] : ((const int*)p)[e];
}

// ---------------------------------------------------------------------------
// CSR build: histogram of dst
__global__ __launch_bounds__(256) void hist_k(
    const void* __restrict__ dstp, const int* __restrict__ flag,
    int* __restrict__ hist)
{
    int e = blockIdx.x * 256 + threadIdx.x;
    if (e >= EE) return;
    atomicAdd(&hist[load_idx(dstp, e, *flag)], 1);
}

__global__ __launch_bounds__(SCAN_B) void scan1_k(
    const int* __restrict__ hist, int* __restrict__ incl, int* __restrict__ bsum)
{
    __shared__ int sh[SCAN_B];
    int t = threadIdx.x;
    int i = blockIdx.x * SCAN_B + t;
    int v = (i < NN) ? hist[i] : 0;
    sh[t] = v;
    __syncthreads();
    for (int off = 1; off < SCAN_B; off <<= 1) {
        int x = (t >= off) ? sh[t - off] : 0;
        __syncthreads();
        sh[t] += x;
        __syncthreads();
    }
    if (i < NN) incl[i] = sh[t];
    if (t == SCAN_B - 1) bsum[blockIdx.x] = sh[t];
}

__global__ __launch_bounds__(512) void scan2_k(int* __restrict__ bsum) {
    __shared__ int sh[512];
    int t = threadIdx.x;
    sh[t] = (t < NBLK) ? bsum[t] : 0;
    __syncthreads();
    for (int off = 1; off < 512; off <<= 1) {
        int x = (t >= off) ? sh[t - off] : 0;
        __syncthreads();
        sh[t] += x;
        __syncthreads();
    }
    if (t < NBLK) bsum[t] = sh[t];
}

__global__ __launch_bounds__(SCAN_B) void scan3_k(
    const int* __restrict__ hist, const int* __restrict__ incl,
    const int* __restrict__ bsum, int* __restrict__ row_ptr,
    int* __restrict__ cursor)
{
    int b = blockIdx.x;
    int i = b * SCAN_B + threadIdx.x;
    if (i < NN) {
        int ex = incl[i] - hist[i] + (b > 0 ? bsum[b - 1] : 0);
        row_ptr[i] = ex;
        cursor[i] = ex;
    }
    if (i == 0) row_ptr[NN] = EE;
}

__global__ __launch_bounds__(256) void fill_k(
    const void* __restrict__ srcp, const void* __restrict__ dstp,
    const int* __restrict__ flag, int* __restrict__ cursor,
    int* __restrict__ sorted_src)
{
    int e = blockIdx.x * 256 + threadIdx.x;
    if (e >= EE) return;
    int is64 = *flag;
    int d = load_idx(dstp, e, is64);
    int pos = atomicAdd(&cursor[d], 1);
    sorted_src[pos] = load_idx(srcp, e, is64);
}

// ---------------------------------------------------------------------------
// 128-col GEMM, r5 verbatim (verified: 64 VGPR, (256,4), no scratch). Used
// only for x0 = x @ W_in + b_in. DO NOT restructure (r1/r2/r8 evidence).
__global__ __launch_bounds__(256, 4) void gemm128(
    const float* __restrict__ A, const float* __restrict__ Wp,
    const float* __restrict__ bias, float* __restrict__ out,
    float* __restrict__ statsp, int nrows)
{
    __shared__ float As[HH * AST];   // A^T [k][r]
    const int t = threadIdx.x;
    const int tx = t & 31;           // output cols 4*tx..4*tx+3
    const int ty = t >> 5;           // rows 8*ty..8*ty+7
    const int lane = t & 63, w = t >> 6;
    const int row0 = blockIdx.x * TR;

#pragma unroll
    for (int i = 0; i < 8; ++i) {
        int r = (i & 3) * 16 + (lane & 15);
        int k4 = ((i >> 2) * 4 + w) * 4 + (lane >> 4);
        float4 v = {0.f, 0.f, 0.f, 0.f};
        if (row0 + r < nrows)
            v = ((const float4*)(A + (size_t)(row0 + r) * HH))[k4];
        int k = k4 * 4;
        As[(k + 0) * AST + r] = v.x;
        As[(k + 1) * AST + r] = v.y;
        As[(k + 2) * AST + r] = v.z;
        As[(k + 3) * AST + r] = v.w;
    }
    __syncthreads();

    float acc[8][4];
#pragma unroll
    for (int ii = 0; ii < 8; ++ii)
#pragma unroll
        for (int j = 0; j < 4; ++j) acc[ii][j] = 0.f;

    const float4* W4 = (const float4*)Wp;   // row k -> W4[k*32 + tx]
    float4 wbuf[4];
#pragma unroll
    for (int kk = 0; kk < 4; ++kk) wbuf[kk] = W4[kk * 32 + tx];

    for (int k0 = 0; k0 < HH; k0 += 4) {
        float4 wn[4];
        const bool more = (k0 + 4 < HH);
#pragma unroll
        for (int kk = 0; kk < 4; ++kk) {
            if (more) wn[kk] = W4[(k0 + 4 + kk) * 32 + tx];  // prefetch next chunk
            int k = k0 + kk;
            const float* ap = &As[k * AST + ty * 8];
            float4 a0 = *(const float4*)ap;
            float4 a1 = *(const float4*)(ap + 4);
            float a[8] = {a0.x, a0.y, a0.z, a0.w, a1.x, a1.y, a1.z, a1.w};
#pragma unroll
            for (int ii = 0; ii < 8; ++ii) {
                acc[ii][0] += a[ii] * wbuf[kk].x;
                acc[ii][1] += a[ii] * wbuf[kk].y;
                acc[ii][2] += a[ii] * wbuf[kk].z;
                acc[ii][3] += a[ii] * wbuf[kk].w;
            }
        }
        if (more) {
#pragma unroll
            for (int kk = 0; kk < 4; ++kk) wbuf[kk] = wn[kk];
        }
    }

    float4 b4 = {0.f, 0.f, 0.f, 0.f};
    if (bias) b4 = ((const float4*)bias)[tx];
#pragma unroll
    for (int ii = 0; ii < 8; ++ii) {
        int r = row0 + ty * 8 + ii;
        if (r < nrows) {
            float4 v = {acc[ii][0] + b4.x, acc[ii][1] + b4.y,
                        acc[ii][2] + b4.z, acc[ii][3] + b4.w};
            ((float4*)out)[(size_t)r * 32 + tx] = v;
        }
    }
    (void)statsp;
}

// ---------------------------------------------------------------------------
// FUSED layer kernel (r10-verified, byte-identical): phase A gather -> As
// (transposed, BN+ReLU+residual fold in-flight), phase B r5-verified GEMM.
// (256,2): proven no-spill bound. LDS 34816 -> up to 4 blocks/CU.
template <bool BN, bool DOSTATS>
__global__ __launch_bounds__(256, 2) void fused_layer(
    const float* __restrict__ z, const int* __restrict__ row_ptr,
    const int* __restrict__ sorted_src,
    const float* __restrict__ stats,    // [256] sum,sumsq of z (BN only)
    const float* __restrict__ gamma, const float* __restrict__ beta,
    const float* __restrict__ resid,    // x0
    const float* __restrict__ Wp, float* __restrict__ out,
    float* __restrict__ statsp, int nrows)
{
    __shared__ float As[HH * AST];   // A^T [k][r]
    const int t = threadIdx.x;
    const int tx = t & 31;           // output cols 4*tx..4*tx+3
    const int ty = t >> 5;           // rows 8*ty..8*ty+7
    const int lane = t & 63, w = t >> 6;
    const int row0 = blockIdx.x * TR;

    const int half = lane >> 5;      // edge stream of the pair
    const int c4 = lane & 31;        // float4 channel index

    float4 sc = {1.f, 1.f, 1.f, 1.f}, sh = {0.f, 0.f, 0.f, 0.f};
    if (BN) {
        const float invN = 1.f / (float)NN;
        float4 s  = ((const float4*)stats)[c4];
        float4 s2 = ((const float4*)(stats + 128))[c4];
        float4 g  = ((const float4*)gamma)[c4];
        float4 b  = ((const float4*)beta)[c4];
        float m, var;
        m = s.x * invN; var = s2.x * invN - m * m;
        sc.x = rsqrtf(var + EPS_C) * g.x; sh.x = b.x - m * sc.x;
        m = s.y * invN; var = s2.y * invN - m * m;
        sc.y = rsqrtf(var + EPS_C) * g.y; sh.y = b.y - m * sc.y;
        m = s.z * invN; var = s2.z * invN - m * m;
        sc.z = rsqrtf(var + EPS_C) * g.z; sh.z = b.z - m * sc.z;
        m = s.w * invN; var = s2.w * invN - m * m;
        sc.w = rsqrtf(var + EPS_C) * g.w; sh.w = b.w - m * sc.w;
    }

    // ---- phase A: gather 16 nodes per wave into As (transposed) ----
    for (int i = 0; i < 16; ++i) {
        int rr = w * 16 + i;
        int node = row0 + rr;
        if (node < nrows) {
            float4 r4v = ((const float4*)(resid + (size_t)node * HH))[c4];
            int e1 = row_ptr[node + 1];
            int e = row_ptr[node] + half;
            float4 acc  = {0.f, 0.f, 0.f, 0.f};
            float4 acc2 = {0.f, 0.f, 0.f, 0.f};
            float4 acc3 = {0.f, 0.f, 0.f, 0.f};
            float4 acc4 = {0.f, 0.f, 0.f, 0.f};
            for (; e + 6 < e1; e += 8) {
                int s0 = sorted_src[e];
                int s1 = sorted_src[e + 2];
                int s2 = sorted_src[e + 4];
                int s3 = sorted_src[e + 6];
                float4 v0 = ((const float4*)(z + (size_t)s0 * HH))[c4];
                float4 v1 = ((const float4*)(z + (size_t)s1 * HH))[c4];
                float4 v2 = ((const float4*)(z + (size_t)s2 * HH))[c4];
                float4 v3 = ((const float4*)(z + (size_t)s3 * HH))[c4];
                if (BN) {
                    v0.x = fmaxf(0.f, v0.x * sc.x + sh.x);
                    v0.y = fmaxf(0.f, v0.y * sc.y + sh.y);
                    v0.z = fmaxf(0.f, v0.z * sc.z + sh.z);
                    v0.w = fmaxf(0.f, v0.w * sc.w + sh.w);
                    v1.x = fmaxf(0.f, v1.x * sc.x + sh.x);
                    v1.y = fmaxf(0.f, v1.y * sc.y + sh.y);
                    v1.z = fmaxf(0.f, v1.z * sc.z + sh.z);
                    v1.w = fmaxf(0.f, v1.w * sc.w + sh.w);
                    v2.x = fmaxf(0.f, v2.x * sc.x + sh.x);
                    v2.y = fmaxf(0.f, v2.y * sc.y + sh.y);
                    v2.z = fmaxf(0.f, v2.z * sc.z + sh.z);
                    v2.w = fmaxf(0.f, v2.w * sc.w + sh.w);
                    v3.x = fmaxf(0.f, v3.x * sc.x + sh.x);
                    v3.y = fmaxf(0.f, v3.y * sc.y + sh.y);
                    v3.z = fmaxf(0.f, v3.z * sc.z + sh.z);
                    v3.w = fmaxf(0.f, v3.w * sc.w + sh.w);
                }
                acc.x  += v0.x; acc.y  += v0.y; acc.z  += v0.z; acc.w  += v0.w;
                acc2.x += v1.x; acc2.y += v1.y; acc2.z += v1.z; acc2.w += v1.w;
                acc3.x += v2.x; acc3.y += v2.y; acc3.z += v2.z; acc3.w += v2.w;
                acc4.x += v3.x; acc4.y += v3.y; acc4.z += v3.z; acc4.w += v3.w;
            }
            for (; e + 2 < e1; e += 4) {
                int s0 = sorted_src[e];
                int s1 = sorted_src[e + 2];
                float4 v0 = ((const float4*)(z + (size_t)s0 * HH))[c4];
                float4 v1 = ((const float4*)(z + (size_t)s1 * HH))[c4];
                if (BN) {
                    v0.x = fmaxf(0.f, v0.x * sc.x + sh.x);
                    v0.y = fmaxf(0.f, v0.y * sc.y + sh.y);
                    v0.z = fmaxf(0.f, v0.z * sc.z + sh.z);
                    v0.w = fmaxf(0.f, v0.w * sc.w + sh.w);
                    v1.x = fmaxf(0.f, v1.x * sc.x + sh.x);
                    v1.y = fmaxf(0.f, v1.y * sc.y + sh.y);
                    v1.z = fmaxf(0.f, v1.z * sc.z + sh.z);
                    v1.w = fmaxf(0.f, v1.w * sc.w + sh.w);
                }
                acc.x  += v0.x; acc.y  += v0.y; acc.z  += v0.z; acc.w  += v0.w;
                acc2.x += v1.x; acc2.y += v1.y; acc2.z += v1.z; acc2.w += v1.w;
            }
            if (e < e1) {
                int s = sorted_src[e];
                float4 v = ((const float4*)(z + (size_t)s * HH))[c4];
                if (BN) {
                    v.x = fmaxf(0.f, v.x * sc.x + sh.x);
                    v.y = fmaxf(0.f, v.y * sc.y + sh.y);
                    v.z = fmaxf(0.f, v.z * sc.z + sh.z);
                    v.w = fmaxf(0.f, v.w * sc.w + sh.w);
                }
                acc.x += v.x; acc.y += v.y; acc.z += v.z; acc.w += v.w;
            }
            acc.x += acc2.x + acc3.x + acc4.x;
            acc.y += acc2.y + acc3.y + acc4.y;
            acc.z += acc2.z + acc3.z + acc4.z;
            acc.w += acc2.w + acc3.w + acc4.w;
            acc.x += __shfl_down(acc.x, 32);
            acc.y += __shfl_down(acc.y, 32);
            acc.z += __shfl_down(acc.z, 32);
            acc.w += __shfl_down(acc.w, 32);
            if (half == 0) {
                const float cA = 1.f - ALPHA_C, cB = ALPHA_C;
                int k = c4 * 4;
                As[(k + 0) * AST + rr] = cA * acc.x + cB * r4v.x;
                As[(k + 1) * AST + rr] = cA * acc.y + cB * r4v.y;
                As[(k + 2) * AST + rr] = cA * acc.z + cB * r4v.z;
                As[(k + 3) * AST + rr] = cA * acc.w + cB * r4v.w;
            }
        }
    }
    __syncthreads();

    // ---- phase B: r5-verified GEMM inner loop ----
    float acc[8][4];
#pragma unroll
    for (int ii = 0; ii < 8; ++ii)
#pragma unroll
        for (int j = 0; j < 4; ++j) acc[ii][j] = 0.f;

    const float4* W4 = (const float4*)Wp;   // row k -> W4[k*32 + tx]
    float4 wbuf[4];
#pragma unroll
    for (int kk = 0; kk < 4; ++kk) wbuf[kk] = W4[kk * 32 + tx];

    for (int k0 = 0; k0 < HH; k0 += 4) {
        float4 wn[4];
        const bool more = (k0 + 4 < HH);
#pragma unroll
        for (int kk = 0; kk < 4; ++kk) {
            if (more) wn[kk] = W4[(k0 + 4 + kk) * 32 + tx];
            int k = k0 + kk;
            const float* ap = &As[k * AST + ty * 8];
            float4 a0 = *(const float4*)ap;
            float4 a1 = *(const float4*)(ap + 4);
            float a[8] = {a0.x, a0.y, a0.z, a0.w, a1.x, a1.y, a1.z, a1.w};
#pragma unroll
            for (int ii = 0; ii < 8; ++ii) {
                acc[ii][0] += a[ii] * wbuf[kk].x;
                acc[ii][1] += a[ii] * wbuf[kk].y;
                acc[ii][2] += a[ii] * wbuf[kk].z;
                acc[ii][3] += a[ii] * wbuf[kk].w;
            }
        }
        if (more) {
#pragma unroll
            for (int kk = 0; kk < 4; ++kk) wbuf[kk] = wn[kk];
        }
    }

    float cs[4] = {0.f, 0.f, 0.f, 0.f}, cq[4] = {0.f, 0.f, 0.f, 0.f};
#pragma unroll
    for (int ii = 0; ii < 8; ++ii) {
        int r = row0 + ty * 8 + ii;
        if (r < nrows) {
            float4 v = {acc[ii][0], acc[ii][1], acc[ii][2], acc[ii][3]};
            ((float4*)out)[(size_t)r * 32 + tx] = v;
            if (DOSTATS) {
                cs[0] += v.x; cq[0] += v.x * v.x;
                cs[1] += v.y; cq[1] += v.y * v.y;
                cs[2] += v.z; cq[2] += v.z * v.z;
                cs[3] += v.w; cq[3] += v.w * v.w;
            }
        }
    }
    if (DOSTATS) {
        __syncthreads();              // all waves done with As -> reuse as scratch
        float* red = As;              // [0..1023]=sum, [1024..2047]=sumsq
#pragma unroll
        for (int j = 0; j < 4; ++j) {
            red[ty * 128 + tx * 4 + j] = cs[j];
            red[1024 + ty * 128 + tx * 4 + j] = cq[j];
        }
        __syncthreads();
        if (t < 128) {
            float s = 0.f, q = 0.f;
#pragma unroll
            for (int g = 0; g < 8; ++g) {
                s += red[g * 128 + t];
                q += red[1024 + g * 128 + t];
            }
            atomicAdd(&statsp[t], s);
            atomicAdd(&statsp[128 + t], q);
        }
    }
}

// ---------------------------------------------------------------------------
// JumpingKnowledge GEMM: out = concat(z0..z3)[N,512] @ Wjk[512,128] + bjk
// r5 verbatim (verified 252-265us / 64 VGPR / no scratch / 0 conflicts).
// out may alias z0. DO NOT fuse with layer 3: r11 proved the fusion loses
// (z3 is L3-resident so the traffic saving is ~16us, while the transposed
// LDS write costs 7.2M bank-conflict cycles and the monolithic block
// serializes gather->GEMM->JK).
__global__ __launch_bounds__(256, 4) void gemm_jk(
    const float* __restrict__ z0, const float* __restrict__ z1,
    const float* __restrict__ z2, const float* __restrict__ z3,
    const float* __restrict__ Wjk, const float* __restrict__ bjk,
    float* __restrict__ out, int nrows)
{
    __shared__ float As[HH * AST];
    const int t = threadIdx.x;
    const int tx = t & 31;
    const int ty = t >> 5;
    const int lane = t & 63, w = t >> 6;
    const int row0 = blockIdx.x * TR;

    float acc[8][4];
#pragma unroll
    for (int ii = 0; ii < 8; ++ii)
#pragma unroll
        for (int j = 0; j < 4; ++j) acc[ii][j] = 0.f;

    const float* srcs[4] = {z0, z1, z2, z3};
    for (int j = 0; j < 4; ++j) {
        if (j) __syncthreads();
        const float* Z = srcs[j];
#pragma unroll
        for (int i = 0; i < 8; ++i) {
            int r = (i & 3) * 16 + (lane & 15);
            int k4 = ((i >> 2) * 4 + w) * 4 + (lane >> 4);
            float4 v = {0.f, 0.f, 0.f, 0.f};
            if (row0 + r < nrows)
                v = ((const float4*)(Z + (size_t)(row0 + r) * HH))[k4];
            int k = k4 * 4;
            As[(k + 0) * AST + r] = v.x;
            As[(k + 1) * AST + r] = v.y;
            As[(k + 2) * AST + r] = v.z;
            As[(k + 3) * AST + r] = v.w;
        }
        __syncthreads();

        const float4* W4 = (const float4*)(Wjk + (size_t)j * 128 * HH);
        float4 wbuf[4];
#pragma unroll
        for (int kk = 0; kk < 4; ++kk) wbuf[kk] = W4[kk * 32 + tx];

        for (int k0 = 0; k0 < HH; k0 += 4) {
            float4 wn[4];
            const bool more = (k0 + 4 < HH);
#pragma unroll
            for (int kk = 0; kk < 4; ++kk) {
                if (more) wn[kk] = W4[(k0 + 4 + kk) * 32 + tx];
                int k = k0 + kk;
                const float* ap = &As[k * AST + ty * 8];
                float4 a0 = *(const float4*)ap;
                float4 a1 = *(const float4*)(ap + 4);
                float a[8] = {a0.x, a0.y, a0.z, a0.w, a1.x, a1.y, a1.z, a1.w};
#pragma unroll
                for (int ii = 0; ii < 8; ++ii) {
                    acc[ii][0] += a[ii] * wbuf[kk].x;
                    acc[ii][1] += a[ii] * wbuf[kk].y;
                    acc[ii][2] += a[ii] * wbuf[kk].z;
                    acc[ii][3] += a[ii] * wbuf[kk].w;
                }
            }
            if (more) {
#pragma unroll
                for (int kk = 0; kk < 4; ++kk) wbuf[kk] = wn[kk];
            }
        }
    }

    float4 b4 = ((const float4*)bjk)[tx];
#pragma unroll
    for (int ii = 0; ii < 8; ++ii) {
        int r = row0 + ty * 8 + ii;
        if (r < nrows) {
            float4 v = {acc[ii][0] + b4.x, acc[ii][1] + b4.y,
                        acc[ii][2] + b4.z, acc[ii][3] + b4.w};
            ((float4*)out)[(size_t)r * 32 + tx] = v;
        }
    }
}

// ---------------------------------------------------------------------------
extern "C" void kernel_launch(void* const* d_in, const int* in_sizes, int n_in,
                              void* d_out, int out_size, void* d_ws, size_t ws_size,
                              hipStream_t stream)
{
    const float* x       = (const float*)d_in[0];
    const float* W_in    = (const float*)d_in[1];
    const float* b_in    = (const float*)d_in[2];
    const float* conv_W  = (const float*)d_in[3];
    const float* bn_g    = (const float*)d_in[4];
    const float* bn_b    = (const float*)d_in[5];
    const float* W_jk    = (const float*)d_in[6];
    const float* b_jk    = (const float*)d_in[7];
    const void*  srcp    = d_in[8];
    const void*  dstp    = d_in[9];

    // Workspace: 5*NH floats (244 MiB) + stats3 + CSR (~7.3 MB) + Wp (384 KB)
    float* ws     = (float*)d_ws;
    float* x0     = ws;                        // [N,H] z0, residual
    float* zs0    = ws + 2 * (size_t)NH;       // z per layer; zs0 reused as JK out
    float* zs1    = ws + 3 * (size_t)NH;
    float* zs2    = ws + 4 * (size_t)NH;
    float* stats3 = ws + 5 * (size_t)NH;       // [3][256] sum/sumsq per BN layer
    int*   flag       = (int*)(stats3 + 768);
    int*   hist       = flag + 1;              // [NN]
    int*   incl       = hist + NN;             // [NN]
    int*   row_ptr    = incl + NN;             // [NN+1]
    int*   cursor     = row_ptr + NN + 1;      // [NN]
    int*   bsum       = cursor + NN;           // [NBLK]
    int*   sorted_src = bsum + NBLK + 1;       // [EE]
    float* Wp         = (float*)(sorted_src + EE);  // [6][128][128]

    const int GEMM_GRID = (NN + TR - 1) / TR;     // 1563
    const int EDGE_GRID = (EE + 255) / 256;       // 6250

    // ---- merged prologue (detect + zero + prep_w), then CSR build ----
    init_k<<<NBLK, 256, 0, stream>>>((const int*)srcp, flag, hist, stats3,
                                     W_in, conv_W, Wp);
    hist_k<<<EDGE_GRID, 256, 0, stream>>>(dstp, flag, hist);
    scan1_k<<<NBLK, SCAN_B, 0, stream>>>(hist, incl, bsum);
    scan2_k<<<1, 512, 0, stream>>>(bsum);
    scan3_k<<<NBLK, SCAN_B, 0, stream>>>(hist, incl, bsum, row_ptr, cursor);
    fill_k<<<EDGE_GRID, 256, 0, stream>>>(srcp, dstp, flag, cursor, sorted_src);

    // ---- x0 = x @ W_in + b_in ----
    gemm128<<<GEMM_GRID, 256, 0, stream>>>(x, Wp, b_in, x0, nullptr, NN);

    // ---- layer 0: act = x0 (no BN), out zs0, stats0 ----
    fused_layer<false, true><<<GEMM_GRID, 256, 0, stream>>>(
        x0, row_ptr, sorted_src, nullptr, nullptr, nullptr, x0,
        Wp + 1 * 16384, zs0, stats3 + 0, NN);
    // ---- layer 1: BN(stats0), out zs1, stats1 ----
    fused_layer<true, true><<<GEMM_GRID, 256, 0, stream>>>(
        zs0, row_ptr, sorted_src, stats3 + 0, bn_g + 0, bn_b + 0, x0,
        Wp + 2 * 16384, zs1, stats3 + 256, NN);
    // ---- layer 2: BN(stats1), out zs2, stats2 ----
    fused_layer<true, true><<<GEMM_GRID, 256, 0, stream>>>(
        zs1, row_ptr, sorted_src, stats3 + 256, bn_g + HH, bn_b + HH, x0,
        Wp + 3 * 16384, zs2, stats3 + 512, NN);
    // ---- layer 3: BN(stats2), out d_out ----
    fused_layer<true, false><<<GEMM_GRID, 256, 0, stream>>>(
        zs2, row_ptr, sorted_src, stats3 + 512, bn_g + 2 * HH, bn_b + 2 * HH, x0,
        Wp + 4 * 16384, (float*)d_out, nullptr, NN);
    // ---- JumpingKnowledge: zs0 = concat(zs0..d_out) @ Wjk + bjk ----
    gemm_jk<<<GEMM_GRID, 256, 0, stream>>>(zs0, zs1, zs2, (const float*)d_out,
                                           W_jk, b_jk, zs0, NN);
    // ---- layer 4: act = zs0 (no BN), out d_out ----
    fused_layer<false, false><<<GEMM_GRID, 256, 0, stream>>>(
        zs0, row_ptr, sorted_src, nullptr, nullptr, nullptr, x0,
        Wp + 5 * 16384, (float*)d_out, nullptr, NN);
}

// Round 13
// 1383.733 us; speedup vs baseline: 1.0750x; 1.0469x over previous
//
#include <hip/hip_runtime.h>
#include <hip/hip_bf16.h>
#include <hip/hip_fp16.h>
#include <cmath>
#include <cstddef>

// Problem constants (from reference)
#define NN 100000
#define HH 128
#define EE 1600000
#define NH (NN * HH)
#define ALPHA_C 0.1f
#define THETA_C 0.5f
#define EPS_C 1e-5f

constexpr int TR = 64;    // rows per GEMM block
constexpr int AST = 68;   // LDS A^T stride (floats): 16B-aligned rows, b128-clean
constexpr int SCAN_B = 256;
constexpr int NBLK = (NN + SCAN_B - 1) / SCAN_B;   // 391 scan blocks

// fp16 pack/unpack helpers -- value-passing only (no frame capture; r3/r4).
__device__ __forceinline__ float4 h2f4(uint2 u) {
    __half2 a = *reinterpret_cast<__half2*>(&u.x);
    __half2 b = *reinterpret_cast<__half2*>(&u.y);
    float2 fa = __half22float2(a);
    float2 fb = __half22float2(b);
    return float4{fa.x, fa.y, fb.x, fb.y};
}
__device__ __forceinline__ uint2 f4h(float4 v) {
    __half2 a = __floats2half2_rn(v.x, v.y);
    __half2 b = __floats2half2_rn(v.z, v.w);
    uint2 u;
    u.x = *reinterpret_cast<unsigned*>(&a);
    u.y = *reinterpret_cast<unsigned*>(&b);
    return u;
}

// ---------------------------------------------------------------------------
// Merged prologue: index-dtype detect (1 thread), hist zero, stats zero, and
// weight prep (blocks 0..383) -- one launch instead of four (r12-verified).
__global__ __launch_bounds__(256) void init_k(
    const int* __restrict__ srcp_i, int* __restrict__ flag,
    int* __restrict__ hist, float* __restrict__ stats3,
    const float* __restrict__ W_in, const float* __restrict__ conv_W,
    float* __restrict__ Wp)
{
    const int b = blockIdx.x, t = threadIdx.x;
    const int i = b * 256 + t;
    if (i < NN) hist[i] = 0;
    if (i < 768) stats3[i] = 0.f;
    if (i == 0) {
        int any = 0;
        for (int k = 0; k < 64; ++k) any |= srcp_i[2 * k + 1];
        *flag = (any == 0) ? 1 : 0;
    }
    if (b < 384) {
        int wi = b >> 6;                         // 0..5
        int idx = (b & 63) * 256 + t;            // 0..16383
        float v;
        if (wi == 0) {
            v = W_in[idx];
        } else {
            float bl = logf(THETA_C / (float)wi + 1.f);
            int k = idx >> 7, c = idx & 127;
            v = bl * conv_W[(size_t)(wi - 1) * 16384 + idx]
                + ((k == c) ? (1.f - bl) : 0.f);
        }
        Wp[(size_t)wi * 16384 + idx] = v;
    }
}

__device__ __forceinline__ int load_idx(const void* p, int e, int is64) {
    return is64 ? (int)((const long long*)p)[e] : ((const int*)p)[e];
}

// ---------------------------------------------------------------------------
// CSR build: histogram of dst
__global__ __launch_bounds__(256) void hist_k(
    const void* __restrict__ dstp, const int* __restrict__ flag,
    int* __restrict__ hist)
{
    int e = blockIdx.x * 256 + threadIdx.x;
    if (e >= EE) return;
    atomicAdd(&hist[load_idx(dstp, e, *flag)], 1);
}

__global__ __launch_bounds__(SCAN_B) void scan1_k(
    const int* __restrict__ hist, int* __restrict__ incl, int* __restrict__ bsum)
{
    __shared__ int sh[SCAN_B];
    int t = threadIdx.x;
    int i = blockIdx.x * SCAN_B + t;
    int v = (i < NN) ? hist[i] : 0;
    sh[t] = v;
    __syncthreads();
    for (int off = 1; off < SCAN_B; off <<= 1) {
        int x = (t >= off) ? sh[t - off] : 0;
        __syncthreads();
        sh[t] += x;
        __syncthreads();
    }
    if (i < NN) incl[i] = sh[t];
    if (t == SCAN_B - 1) bsum[blockIdx.x] = sh[t];
}

__global__ __launch_bounds__(512) void scan2_k(int* __restrict__ bsum) {
    __shared__ int sh[512];
    int t = threadIdx.x;
    sh[t] = (t < NBLK) ? bsum[t] : 0;
    __syncthreads();
    for (int off = 1; off < 512; off <<= 1) {
        int x = (t >= off) ? sh[t - off] : 0;
        __syncthreads();
        sh[t] += x;
        __syncthreads();
    }
    if (t < NBLK) bsum[t] = sh[t];
}

__global__ __launch_bounds__(SCAN_B) void scan3_k(
    const int* __restrict__ hist, const int* __restrict__ incl,
    const int* __restrict__ bsum, int* __restrict__ row_ptr,
    int* __restrict__ cursor)
{
    int b = blockIdx.x;
    int i = b * SCAN_B + threadIdx.x;
    if (i < NN) {
        int ex = incl[i] - hist[i] + (b > 0 ? bsum[b - 1] : 0);
        row_ptr[i] = ex;
        cursor[i] = ex;
    }
    if (i == 0) row_ptr[NN] = EE;
}

__global__ __launch_bounds__(256) void fill_k(
    const void* __restrict__ srcp, const void* __restrict__ dstp,
    const int* __restrict__ flag, int* __restrict__ cursor,
    int* __restrict__ sorted_src)
{
    int e = blockIdx.x * 256 + threadIdx.x;
    if (e >= EE) return;
    int is64 = *flag;
    int d = load_idx(dstp, e, is64);
    int pos = atomicAdd(&cursor[d], 1);
    sorted_src[pos] = load_idx(srcp, e, is64);
}

// ---------------------------------------------------------------------------
// 128-col GEMM, r5 verbatim + optional fp16 shadow copy of the output
// (consumed by the next layer's gather). DO NOT restructure (r1/r2/r8).
__global__ __launch_bounds__(256, 4) void gemm128(
    const float* __restrict__ A, const float* __restrict__ Wp,
    const float* __restrict__ bias, float* __restrict__ out,
    __half* __restrict__ out_h, int nrows)
{
    __shared__ float As[HH * AST];   // A^T [k][r]
    const int t = threadIdx.x;
    const int tx = t & 31;           // output cols 4*tx..4*tx+3
    const int ty = t >> 5;           // rows 8*ty..8*ty+7
    const int lane = t & 63, w = t >> 6;
    const int row0 = blockIdx.x * TR;

#pragma unroll
    for (int i = 0; i < 8; ++i) {
        int r = (i & 3) * 16 + (lane & 15);
        int k4 = ((i >> 2) * 4 + w) * 4 + (lane >> 4);
        float4 v = {0.f, 0.f, 0.f, 0.f};
        if (row0 + r < nrows)
            v = ((const float4*)(A + (size_t)(row0 + r) * HH))[k4];
        int k = k4 * 4;
        As[(k + 0) * AST + r] = v.x;
        As[(k + 1) * AST + r] = v.y;
        As[(k + 2) * AST + r] = v.z;
        As[(k + 3) * AST + r] = v.w;
    }
    __syncthreads();

    float acc[8][4];
#pragma unroll
    for (int ii = 0; ii < 8; ++ii)
#pragma unroll
        for (int j = 0; j < 4; ++j) acc[ii][j] = 0.f;

    const float4* W4 = (const float4*)Wp;   // row k -> W4[k*32 + tx]
    float4 wbuf[4];
#pragma unroll
    for (int kk = 0; kk < 4; ++kk) wbuf[kk] = W4[kk * 32 + tx];

    for (int k0 = 0; k0 < HH; k0 += 4) {
        float4 wn[4];
        const bool more = (k0 + 4 < HH);
#pragma unroll
        for (int kk = 0; kk < 4; ++kk) {
            if (more) wn[kk] = W4[(k0 + 4 + kk) * 32 + tx];  // prefetch next chunk
            int k = k0 + kk;
            const float* ap = &As[k * AST + ty * 8];
            float4 a0 = *(const float4*)ap;
            float4 a1 = *(const float4*)(ap + 4);
            float a[8] = {a0.x, a0.y, a0.z, a0.w, a1.x, a1.y, a1.z, a1.w};
#pragma unroll
            for (int ii = 0; ii < 8; ++ii) {
                acc[ii][0] += a[ii] * wbuf[kk].x;
                acc[ii][1] += a[ii] * wbuf[kk].y;
                acc[ii][2] += a[ii] * wbuf[kk].z;
                acc[ii][3] += a[ii] * wbuf[kk].w;
            }
        }
        if (more) {
#pragma unroll
            for (int kk = 0; kk < 4; ++kk) wbuf[kk] = wn[kk];
        }
    }

    float4 b4 = {0.f, 0.f, 0.f, 0.f};
    if (bias) b4 = ((const float4*)bias)[tx];
#pragma unroll
    for (int ii = 0; ii < 8; ++ii) {
        int r = row0 + ty * 8 + ii;
        if (r < nrows) {
            float4 v = {acc[ii][0] + b4.x, acc[ii][1] + b4.y,
                        acc[ii][2] + b4.z, acc[ii][3] + b4.w};
            ((float4*)out)[(size_t)r * 32 + tx] = v;
            if (out_h) ((uint2*)out_h)[(size_t)r * 32 + tx] = f4h(v);
        }
    }
}

// ---------------------------------------------------------------------------
// FUSED layer kernel (r10-verified structure): phase A gather (now from the
// fp16 shadow: 256 B/row instead of 512 -> halves L3 bytes AND cache-line
// transactions of the dominant phase), phase B r5-verified GEMM.
// Epilogue writes f32 out + optional fp16 shadow for the next layer.
// (256,2): proven no-spill bound. LDS 34816 -> up to 4 blocks/CU.
template <bool BN, bool DOSTATS>
__global__ __launch_bounds__(256, 2) void fused_layer(
    const __half* __restrict__ zh, const int* __restrict__ row_ptr,
    const int* __restrict__ sorted_src,
    const float* __restrict__ stats,    // [256] sum,sumsq of z (BN only)
    const float* __restrict__ gamma, const float* __restrict__ beta,
    const float* __restrict__ resid,    // x0 (f32)
    const float* __restrict__ Wp, float* __restrict__ out,
    __half* __restrict__ out_h, float* __restrict__ statsp, int nrows)
{
    __shared__ float As[HH * AST];   // A^T [k][r]
    const int t = threadIdx.x;
    const int tx = t & 31;           // output cols 4*tx..4*tx+3
    const int ty = t >> 5;           // rows 8*ty..8*ty+7
    const int lane = t & 63, w = t >> 6;
    const int row0 = blockIdx.x * TR;

    const int half = lane >> 5;      // edge stream of the pair
    const int c4 = lane & 31;        // 4-channel group index

    float4 sc = {1.f, 1.f, 1.f, 1.f}, sh = {0.f, 0.f, 0.f, 0.f};
    if (BN) {
        const float invN = 1.f / (float)NN;
        float4 s  = ((const float4*)stats)[c4];
        float4 s2 = ((const float4*)(stats + 128))[c4];
        float4 g  = ((const float4*)gamma)[c4];
        float4 b  = ((const float4*)beta)[c4];
        float m, var;
        m = s.x * invN; var = s2.x * invN - m * m;
        sc.x = rsqrtf(var + EPS_C) * g.x; sh.x = b.x - m * sc.x;
        m = s.y * invN; var = s2.y * invN - m * m;
        sc.y = rsqrtf(var + EPS_C) * g.y; sh.y = b.y - m * sc.y;
        m = s.z * invN; var = s2.z * invN - m * m;
        sc.z = rsqrtf(var + EPS_C) * g.z; sh.z = b.z - m * sc.z;
        m = s.w * invN; var = s2.w * invN - m * m;
        sc.w = rsqrtf(var + EPS_C) * g.w; sh.w = b.w - m * sc.w;
    }

    const uint2* Zh = (const uint2*)zh;   // row stride 32 uint2 (128 halfs)

    // ---- phase A: gather 16 nodes per wave into As (transposed) ----
    for (int i = 0; i < 16; ++i) {
        int rr = w * 16 + i;
        int node = row0 + rr;
        if (node < nrows) {
            float4 r4v = ((const float4*)(resid + (size_t)node * HH))[c4];
            int e1 = row_ptr[node + 1];
            int e = row_ptr[node] + half;
            float4 acc  = {0.f, 0.f, 0.f, 0.f};
            float4 acc2 = {0.f, 0.f, 0.f, 0.f};
            float4 acc3 = {0.f, 0.f, 0.f, 0.f};
            float4 acc4 = {0.f, 0.f, 0.f, 0.f};
            for (; e + 6 < e1; e += 8) {
                int s0 = sorted_src[e];
                int s1 = sorted_src[e + 2];
                int s2 = sorted_src[e + 4];
                int s3 = sorted_src[e + 6];
                float4 v0 = h2f4(Zh[(size_t)s0 * 32 + c4]);
                float4 v1 = h2f4(Zh[(size_t)s1 * 32 + c4]);
                float4 v2 = h2f4(Zh[(size_t)s2 * 32 + c4]);
                float4 v3 = h2f4(Zh[(size_t)s3 * 32 + c4]);
                if (BN) {
                    v0.x = fmaxf(0.f, v0.x * sc.x + sh.x);
                    v0.y = fmaxf(0.f, v0.y * sc.y + sh.y);
                    v0.z = fmaxf(0.f, v0.z * sc.z + sh.z);
                    v0.w = fmaxf(0.f, v0.w * sc.w + sh.w);
                    v1.x = fmaxf(0.f, v1.x * sc.x + sh.x);
                    v1.y = fmaxf(0.f, v1.y * sc.y + sh.y);
                    v1.z = fmaxf(0.f, v1.z * sc.z + sh.z);
                    v1.w = fmaxf(0.f, v1.w * sc.w + sh.w);
                    v2.x = fmaxf(0.f, v2.x * sc.x + sh.x);
                    v2.y = fmaxf(0.f, v2.y * sc.y + sh.y);
                    v2.z = fmaxf(0.f, v2.z * sc.z + sh.z);
                    v2.w = fmaxf(0.f, v2.w * sc.w + sh.w);
                    v3.x = fmaxf(0.f, v3.x * sc.x + sh.x);
                    v3.y = fmaxf(0.f, v3.y * sc.y + sh.y);
                    v3.z = fmaxf(0.f, v3.z * sc.z + sh.z);
                    v3.w = fmaxf(0.f, v3.w * sc.w + sh.w);
                }
                acc.x  += v0.x; acc.y  += v0.y; acc.z  += v0.z; acc.w  += v0.w;
                acc2.x += v1.x; acc2.y += v1.y; acc2.z += v1.z; acc2.w += v1.w;
                acc3.x += v2.x; acc3.y += v2.y; acc3.z += v2.z; acc3.w += v2.w;
                acc4.x += v3.x; acc4.y += v3.y; acc4.z += v3.z; acc4.w += v3.w;
            }
            for (; e + 2 < e1; e += 4) {
                int s0 = sorted_src[e];
                int s1 = sorted_src[e + 2];
                float4 v0 = h2f4(Zh[(size_t)s0 * 32 + c4]);
                float4 v1 = h2f4(Zh[(size_t)s1 * 32 + c4]);
                if (BN) {
                    v0.x = fmaxf(0.f, v0.x * sc.x + sh.x);
                    v0.y = fmaxf(0.f, v0.y * sc.y + sh.y);
                    v0.z = fmaxf(0.f, v0.z * sc.z + sh.z);
                    v0.w = fmaxf(0.f, v0.w * sc.w + sh.w);
                    v1.x = fmaxf(0.f, v1.x * sc.x + sh.x);
                    v1.y = fmaxf(0.f, v1.y * sc.y + sh.y);
                    v1.z = fmaxf(0.f, v1.z * sc.z + sh.z);
                    v1.w = fmaxf(0.f, v1.w * sc.w + sh.w);
                }
                acc.x  += v0.x; acc.y  += v0.y; acc.z  += v0.z; acc.w  += v0.w;
                acc2.x += v1.x; acc2.y += v1.y; acc2.z += v1.z; acc2.w += v1.w;
            }
            if (e < e1) {
                int s = sorted_src[e];
                float4 v = h2f4(Zh[(size_t)s * 32 + c4]);
                if (BN) {
                    v.x = fmaxf(0.f, v.x * sc.x + sh.x);
                    v.y = fmaxf(0.f, v.y * sc.y + sh.y);
                    v.z = fmaxf(0.f, v.z * sc.z + sh.z);
                    v.w = fmaxf(0.f, v.w * sc.w + sh.w);
                }
                acc.x += v.x; acc.y += v.y; acc.z += v.z; acc.w += v.w;
            }
            acc.x += acc2.x + acc3.x + acc4.x;
            acc.y += acc2.y + acc3.y + acc4.y;
            acc.z += acc2.z + acc3.z + acc4.z;
            acc.w += acc2.w + acc3.w + acc4.w;
            acc.x += __shfl_down(acc.x, 32);
            acc.y += __shfl_down(acc.y, 32);
            acc.z += __shfl_down(acc.z, 32);
            acc.w += __shfl_down(acc.w, 32);
            if (half == 0) {
                const float cA = 1.f - ALPHA_C, cB = ALPHA_C;
                int k = c4 * 4;
                As[(k + 0) * AST + rr] = cA * acc.x + cB * r4v.x;
                As[(k + 1) * AST + rr] = cA * acc.y + cB * r4v.y;
                As[(k + 2) * AST + rr] = cA * acc.z + cB * r4v.z;
                As[(k + 3) * AST + rr] = cA * acc.w + cB * r4v.w;
            }
        }
    }
    __syncthreads();

    // ---- phase B: r5-verified GEMM inner loop ----
    float acc[8][4];
#pragma unroll
    for (int ii = 0; ii < 8; ++ii)
#pragma unroll
        for (int j = 0; j < 4; ++j) acc[ii][j] = 0.f;

    const float4* W4 = (const float4*)Wp;   // row k -> W4[k*32 + tx]
    float4 wbuf[4];
#pragma unroll
    for (int kk = 0; kk < 4; ++kk) wbuf[kk] = W4[kk * 32 + tx];

    for (int k0 = 0; k0 < HH; k0 += 4) {
        float4 wn[4];
        const bool more = (k0 + 4 < HH);
#pragma unroll
        for (int kk = 0; kk < 4; ++kk) {
            if (more) wn[kk] = W4[(k0 + 4 + kk) * 32 + tx];
            int k = k0 + kk;
            const float* ap = &As[k * AST + ty * 8];
            float4 a0 = *(const float4*)ap;
            float4 a1 = *(const float4*)(ap + 4);
            float a[8] = {a0.x, a0.y, a0.z, a0.w, a1.x, a1.y, a1.z, a1.w};
#pragma unroll
            for (int ii = 0; ii < 8; ++ii) {
                acc[ii][0] += a[ii] * wbuf[kk].x;
                acc[ii][1] += a[ii] * wbuf[kk].y;
                acc[ii][2] += a[ii] * wbuf[kk].z;
                acc[ii][3] += a[ii] * wbuf[kk].w;
            }
        }
        if (more) {
#pragma unroll
            for (int kk = 0; kk < 4; ++kk) wbuf[kk] = wn[kk];
        }
    }

    float cs[4] = {0.f, 0.f, 0.f, 0.f}, cq[4] = {0.f, 0.f, 0.f, 0.f};
#pragma unroll
    for (int ii = 0; ii < 8; ++ii) {
        int r = row0 + ty * 8 + ii;
        if (r < nrows) {
            float4 v = {acc[ii][0], acc[ii][1], acc[ii][2], acc[ii][3]};
            ((float4*)out)[(size_t)r * 32 + tx] = v;
            if (out_h) ((uint2*)out_h)[(size_t)r * 32 + tx] = f4h(v);
            if (DOSTATS) {
                cs[0] += v.x; cq[0] += v.x * v.x;
                cs[1] += v.y; cq[1] += v.y * v.y;
                cs[2] += v.z; cq[2] += v.z * v.z;
                cs[3] += v.w; cq[3] += v.w * v.w;
            }
        }
    }
    if (DOSTATS) {
        __syncthreads();              // all waves done with As -> reuse as scratch
        float* red = As;              // [0..1023]=sum, [1024..2047]=sumsq
#pragma unroll
        for (int j = 0; j < 4; ++j) {
            red[ty * 128 + tx * 4 + j] = cs[j];
            red[1024 + ty * 128 + tx * 4 + j] = cq[j];
        }
        __syncthreads();
        if (t < 128) {
            float s = 0.f, q = 0.f;
#pragma unroll
            for (int g = 0; g < 8; ++g) {
                s += red[g * 128 + t];
                q += red[1024 + g * 128 + t];
            }
            atomicAdd(&statsp[t], s);
            atomicAdd(&statsp[128 + t], q);
        }
    }
}

// ---------------------------------------------------------------------------
// JumpingKnowledge GEMM: out = concat(z0..z3)[N,512] @ Wjk[512,128] + bjk
// r5 verbatim + optional fp16 shadow of the output (layer-4 gather input).
// out may alias z0. DO NOT fuse with layer 3 (r11: bank conflicts + serial
// critical path lose more than the L3-resident traffic saving).
__global__ __launch_bounds__(256, 4) void gemm_jk(
    const float* __restrict__ z0, const float* __restrict__ z1,
    const float* __restrict__ z2, const float* __restrict__ z3,
    const float* __restrict__ Wjk, const float* __restrict__ bjk,
    float* __restrict__ out, __half* __restrict__ out_h, int nrows)
{
    __shared__ float As[HH * AST];
    const int t = threadIdx.x;
    const int tx = t & 31;
    const int ty = t >> 5;
    const int lane = t & 63, w = t >> 6;
    const int row0 = blockIdx.x * TR;

    float acc[8][4];
#pragma unroll
    for (int ii = 0; ii < 8; ++ii)
#pragma unroll
        for (int j = 0; j < 4; ++j) acc[ii][j] = 0.f;

    const float* srcs[4] = {z0, z1, z2, z3};
    for (int j = 0; j < 4; ++j) {
        if (j) __syncthreads();
        const float* Z = srcs[j];
#pragma unroll
        for (int i = 0; i < 8; ++i) {
            int r = (i & 3) * 16 + (lane & 15);
            int k4 = ((i >> 2) * 4 + w) * 4 + (lane >> 4);
            float4 v = {0.f, 0.f, 0.f, 0.f};
            if (row0 + r < nrows)
                v = ((const float4*)(Z + (size_t)(row0 + r) * HH))[k4];
            int k = k4 * 4;
            As[(k + 0) * AST + r] = v.x;
            As[(k + 1) * AST + r] = v.y;
            As[(k + 2) * AST + r] = v.z;
            As[(k + 3) * AST + r] = v.w;
        }
        __syncthreads();

        const float4* W4 = (const float4*)(Wjk + (size_t)j * 128 * HH);
        float4 wbuf[4];
#pragma unroll
        for (int kk = 0; kk < 4; ++kk) wbuf[kk] = W4[kk * 32 + tx];

        for (int k0 = 0; k0 < HH; k0 += 4) {
            float4 wn[4];
            const bool more = (k0 + 4 < HH);
#pragma unroll
            for (int kk = 0; kk < 4; ++kk) {
                if (more) wn[kk] = W4[(k0 + 4 + kk) * 32 + tx];
                int k = k0 + kk;
                const float* ap = &As[k * AST + ty * 8];
                float4 a0 = *(const float4*)ap;
                float4 a1 = *(const float4*)(ap + 4);
                float a[8] = {a0.x, a0.y, a0.z, a0.w, a1.x, a1.y, a1.z, a1.w};
#pragma unroll
                for (int ii = 0; ii < 8; ++ii) {
                    acc[ii][0] += a[ii] * wbuf[kk].x;
                    acc[ii][1] += a[ii] * wbuf[kk].y;
                    acc[ii][2] += a[ii] * wbuf[kk].z;
                    acc[ii][3] += a[ii] * wbuf[kk].w;
                }
            }
            if (more) {
#pragma unroll
                for (int kk = 0; kk < 4; ++kk) wbuf[kk] = wn[kk];
            }
        }
    }

    float4 b4 = ((const float4*)bjk)[tx];
#pragma unroll
    for (int ii = 0; ii < 8; ++ii) {
        int r = row0 + ty * 8 + ii;
        if (r < nrows) {
            float4 v = {acc[ii][0] + b4.x, acc[ii][1] + b4.y,
                        acc[ii][2] + b4.z, acc[ii][3] + b4.w};
            ((float4*)out)[(size_t)r * 32 + tx] = v;
            if (out_h) ((uint2*)out_h)[(size_t)r * 32 + tx] = f4h(v);
        }
    }
}

// ---------------------------------------------------------------------------
extern "C" void kernel_launch(void* const* d_in, const int* in_sizes, int n_in,
                              void* d_out, int out_size, void* d_ws, size_t ws_size,
                              hipStream_t stream)
{
    const float* x       = (const float*)d_in[0];
    const float* W_in    = (const float*)d_in[1];
    const float* b_in    = (const float*)d_in[2];
    const float* conv_W  = (const float*)d_in[3];
    const float* bn_g    = (const float*)d_in[4];
    const float* bn_b    = (const float*)d_in[5];
    const float* W_jk    = (const float*)d_in[6];
    const float* b_jk    = (const float*)d_in[7];
    const void*  srcp    = d_in[8];
    const void*  dstp    = d_in[9];

    // Workspace: 5*NH floats (244 MiB) + stats3 + CSR (~7.3 MB) + Wp (384 KB)
    // Old msg slot (ws+NH, NH floats) now holds two fp16 ping-pong shadows.
    float* ws     = (float*)d_ws;
    float* x0     = ws;                        // [N,H] z0 f32, residual
    __half* hb0   = (__half*)(ws + (size_t)NH);         // fp16 shadow A
    __half* hb1   = hb0 + (size_t)NH;                   // fp16 shadow B
    float* zs0    = ws + 2 * (size_t)NH;       // z per layer; zs0 reused as JK out
    float* zs1    = ws + 3 * (size_t)NH;
    float* zs2    = ws + 4 * (size_t)NH;
    float* stats3 = ws + 5 * (size_t)NH;       // [3][256] sum/sumsq per BN layer
    int*   flag       = (int*)(stats3 + 768);
    int*   hist       = flag + 1;              // [NN]
    int*   incl       = hist + NN;             // [NN]
    int*   row_ptr    = incl + NN;             // [NN+1]
    int*   cursor     = row_ptr + NN + 1;      // [NN]
    int*   bsum       = cursor + NN;           // [NBLK]
    int*   sorted_src = bsum + NBLK + 1;       // [EE]
    float* Wp         = (float*)(sorted_src + EE);  // [6][128][128]

    const int GEMM_GRID = (NN + TR - 1) / TR;     // 1563
    const int EDGE_GRID = (EE + 255) / 256;       // 6250

    // ---- merged prologue (detect + zero + prep_w), then CSR build ----
    init_k<<<NBLK, 256, 0, stream>>>((const int*)srcp, flag, hist, stats3,
                                     W_in, conv_W, Wp);
    hist_k<<<EDGE_GRID, 256, 0, stream>>>(dstp, flag, hist);
    scan1_k<<<NBLK, SCAN_B, 0, stream>>>(hist, incl, bsum);
    scan2_k<<<1, 512, 0, stream>>>(bsum);
    scan3_k<<<NBLK, SCAN_B, 0, stream>>>(hist, incl, bsum, row_ptr, cursor);
    fill_k<<<EDGE_GRID, 256, 0, stream>>>(srcp, dstp, flag, cursor, sorted_src);

    // ---- x0 = x @ W_in + b_in  (+ fp16 shadow hb0) ----
    gemm128<<<GEMM_GRID, 256, 0, stream>>>(x, Wp, b_in, x0, hb0, NN);

    // ---- layer 0: gather(hb0), out zs0 + hb1, stats0 ----
    fused_layer<false, true><<<GEMM_GRID, 256, 0, stream>>>(
        hb0, row_ptr, sorted_src, nullptr, nullptr, nullptr, x0,
        Wp + 1 * 16384, zs0, hb1, stats3 + 0, NN);
    // ---- layer 1: BN(stats0), gather(hb1), out zs1 + hb0, stats1 ----
    fused_layer<true, true><<<GEMM_GRID, 256, 0, stream>>>(
        hb1, row_ptr, sorted_src, stats3 + 0, bn_g + 0, bn_b + 0, x0,
        Wp + 2 * 16384, zs1, hb0, stats3 + 256, NN);
    // ---- layer 2: BN(stats1), gather(hb0), out zs2 + hb1, stats2 ----
    fused_layer<true, true><<<GEMM_GRID, 256, 0, stream>>>(
        hb0, row_ptr, sorted_src, stats3 + 256, bn_g + HH, bn_b + HH, x0,
        Wp + 3 * 16384, zs2, hb1, stats3 + 512, NN);
    // ---- layer 3: BN(stats2), gather(hb1), out d_out (no shadow) ----
    fused_layer<true, false><<<GEMM_GRID, 256, 0, stream>>>(
        hb1, row_ptr, sorted_src, stats3 + 512, bn_g + 2 * HH, bn_b + 2 * HH, x0,
        Wp + 4 * 16384, (float*)d_out, nullptr, nullptr, NN);
    // ---- JumpingKnowledge: zs0 = concat(zs0..d_out) @ Wjk + bjk (+ hb0) ----
    gemm_jk<<<GEMM_GRID, 256, 0, stream>>>(zs0, zs1, zs2, (const float*)d_out,
                                           W_jk, b_jk, zs0, hb0, NN);
    // ---- layer 4: gather(hb0), out d_out ----
    fused_layer<false, false><<<GEMM_GRID, 256, 0, stream>>>(
        hb0, row_ptr, sorted_src, nullptr, nullptr, nullptr, x0,
        Wp + 5 * 16384, (float*)d_out, nullptr, nullptr, NN);
}